// Round 6
// baseline (530.601 us; speedup 1.0000x reference)
//
#include <hip/hip_runtime.h>
#include <hip/hip_bf16.h>

// ---------------------------------------------------------------------------
// HoRA linear: out = x @ (base_w + (150*ifft2(sparse_spectrum)) @ A)^T + b
// M=8192, N=4096, K=4096.  bf16 MFMA GEMM with f32 accumulate.
// GEMM: 256x256 tile, BK=64, 8 waves, 16x16x32 MFMA (proven conflict-free
// l15 read pattern), ONE barrier + ONE vmcnt per K-tile; all 24 frag reads
// issued up-front so compiler's fine-grained lgkmcnt overlaps them with the
// 64 MFMAs (kills the read/MFMA phase serialization of r2/r3).
// ---------------------------------------------------------------------------

#define OUTF 4096
#define INF  4096
#define NFREQ 10000
#define MDIM 8192
#define KT   (INF / 64)

typedef __attribute__((ext_vector_type(8))) short bf16x8;
typedef __attribute__((ext_vector_type(4))) float f32x4;

__device__ __forceinline__ unsigned int bf16pack2(float a, float b) {
    unsigned int ua = __builtin_bit_cast(unsigned int, a);
    unsigned int ub = __builtin_bit_cast(unsigned int, b);
    ua = (ua + 0x7fffu + ((ua >> 16) & 1u)) >> 16;          // RNE
    ub = (ub + 0x7fffu + ((ub >> 16) & 1u)) & 0xffff0000u;  // RNE, keep high
    return ua | ub;
}

__device__ __forceinline__ void async_copy16(const void* g, void* l) {
    __builtin_amdgcn_global_load_lds(
        (__attribute__((address_space(1))) void*)(g),
        (__attribute__((address_space(3))) void*)(l),
        16, 0, 0);
}

// ---------------------------------------------------------------------------
// Kernel 1a: compact nnz per chunk (4 blocks, deterministic ballot prefix).
// ---------------------------------------------------------------------------
__global__ __launch_bounds__(256) void compact_kernel(
        const float* __restrict__ spectrum, const int* __restrict__ idx,
        int2* __restrict__ cjk, int* __restrict__ ccnt) {
    const int p   = blockIdx.x;          // chunk 0..3
    const int tid = threadIdx.x;
    const int wv  = tid >> 6, ln = tid & 63;
    __shared__ int wcnt[4];
    int cnt = 0;
    for (int i0 = wv * 64; i0 < NFREQ; i0 += 256) {
        const int i = i0 + ln;
        bool m = (i < NFREQ) && ((idx[i] >> 14) == p);
        cnt += __popcll(__ballot(m));
    }
    if (ln == 0) wcnt[wv] = cnt;
    __syncthreads();
    int base = 0;
    for (int w = 0; w < wv; ++w) base += wcnt[w];
    for (int i0 = wv * 64; i0 < NFREQ; i0 += 256) {
        const int i = i0 + ln;
        bool m = false; int id = 0;
        if (i < NFREQ) { id = idx[i]; m = ((id >> 14) == p); }
        unsigned long long bal = __ballot(m);
        if (m) {
            int pos = base + __popcll(bal & ((1ull << ln) - 1ull));
            if (pos < 4096)
                cjk[p * 4096 + pos] =
                    make_int2(id & 16383, __builtin_bit_cast(int, spectrum[i]));
        }
        base += __popcll(bal);
    }
    if (tid == 0) {
        int t = wcnt[0] + wcnt[1] + wcnt[2] + wcnt[3];
        ccnt[p] = (t < 4096) ? t : 4096;
    }
}

// ---------------------------------------------------------------------------
// Kernel 1b: B[o][r] = (150/16384) * sum_nnz val * cos(2*pi*phase/16384)
// ---------------------------------------------------------------------------
__global__ __launch_bounds__(256) void buildB_kernel(
        const int2* __restrict__ cjk, const int* __restrict__ ccnt,
        float* __restrict__ Bout) {
    __shared__ int2  s_jkv[4096];
    __shared__ float s_part[4][64];
    const int tid  = threadIdx.x;
    const int gid0 = blockIdx.x * 64;
    const int p    = gid0 >> 14;
    const int cnt  = ccnt[p];
    for (int t = tid; t < cnt; t += 256) s_jkv[t] = cjk[p * 4096 + t];
    __syncthreads();
    const int qtr  = tid >> 6;
    const int ol   = tid & 63;
    const int gid  = gid0 + ol;
    const int o    = gid >> 4;
    const int r    = gid & 15;
    const int m    = o & 1023;
    const int qlen = (cnt + 3) >> 2;
    const int t0   = qtr * qlen;
    const int t1   = (t0 + qlen < cnt) ? t0 + qlen : cnt;
    const float c  = 6.283185307179586f / 16384.f;
    float acc = 0.f;
    for (int t = t0; t < t1; ++t) {
        const int2 jv = s_jkv[t];
        const int j = jv.x >> 4, k = jv.x & 15;
        int ph = (((j * m) & 1023) << 4) + (((k * r) & 15) << 10);
        acc += __builtin_bit_cast(float, jv.y) * __cosf((float)(ph & 16383) * c);
    }
    s_part[qtr][ol] = acc;
    __syncthreads();
    if (tid < 64) {
        float s = s_part[0][tid] + s_part[1][tid] + s_part[2][tid] + s_part[3][tid];
        Bout[gid0 + tid] = s * (150.f / 16384.f);
    }
}

// ---------------------------------------------------------------------------
// Kernel 2: W_bf16[n][k] = bf16(base_w[n][k] + sum_r Bs[n][r] * A[r][k])
// ---------------------------------------------------------------------------
__global__ __launch_bounds__(256) void build_w_kernel(
        const float* __restrict__ bw, const float* __restrict__ A,
        const float* __restrict__ Bs, unsigned short* __restrict__ W) {
    const int n0 = blockIdx.x * 8;
    __shared__ float sB[8][16];
    if (threadIdx.x < 128)
        ((float*)sB)[threadIdx.x] = Bs[n0 * 16 + threadIdx.x];
    __syncthreads();
    const float4* A4 = (const float4*)A;
    const float4* bw4 = (const float4*)bw;
    uint2* W2 = (uint2*)W;
#pragma unroll 1
    for (int q = 0; q < 4; ++q) {
        const int c4 = threadIdx.x + q * 256;
        float4 a[16];
#pragma unroll
        for (int r = 0; r < 16; ++r) a[r] = A4[r * 1024 + c4];
#pragma unroll 1
        for (int nn = 0; nn < 8; ++nn) {
            const int n = n0 + nn;
            float4 wv = bw4[n * 1024 + c4];
#pragma unroll
            for (int r = 0; r < 16; ++r) {
                float s = sB[nn][r];
                wv.x += s * a[r].x; wv.y += s * a[r].y;
                wv.z += s * a[r].z; wv.w += s * a[r].w;
            }
            W2[n * 1024 + c4] = make_uint2(bf16pack2(wv.x, wv.y),
                                           bf16pack2(wv.z, wv.w));
        }
    }
}

// ---------------------------------------------------------------------------
// Kernel 3: x (f32) -> bf16
// ---------------------------------------------------------------------------
__global__ __launch_bounds__(256) void cvt_x_kernel(
        const float4* __restrict__ x, uint2* __restrict__ xb, int n4) {
    for (int i = blockIdx.x * blockDim.x + threadIdx.x; i < n4;
         i += gridDim.x * blockDim.x) {
        float4 v = x[i];
        xb[i] = make_uint2(bf16pack2(v.x, v.y), bf16pack2(v.z, v.w));
    }
}

// ---------------------------------------------------------------------------
// Kernel 4: 256x256-tile 8-wave bf16 GEMM, 16x16x32 MFMA.
// Per K-tile: {24 ds_read_b128 (progressive order); 8 global_load_lds of
// tile s+1 -> OTH; 64 MFMA (compiler interleaves lgkmcnt waits so reads
// overlap MFMA); vmcnt(0); s_barrier}.
// Hazard ledger: all tile s-1 reads retired via MFMA data-deps before the
// barrier -> staging OTH during tile s is WAR-safe for every wave; vmcnt(0)
// before the barrier retires tile s+1's staging -> RAW-safe after it.
// ---------------------------------------------------------------------------
__global__ __launch_bounds__(512, 2) void gemm256_kernel(
        const unsigned short* __restrict__ Xb,
        const unsigned short* __restrict__ Wb,
        const float* __restrict__ bias, float* __restrict__ C) {
    __shared__ __align__(1024) char lds[131072];

    const int tid  = threadIdx.x;
    const int lane = tid & 63;
    const int wid  = tid >> 6;
    const int wm   = wid >> 2;   // 0..1
    const int wn   = wid & 3;    // 0..3

    // XCD-bijective swizzle: nwg=512, divisible by 8.
    int bid = blockIdx.x;
    bid = (bid & 7) * 64 + (bid >> 3);
    const int tm = bid >> 4;     // 0..31  M tile
    const int tn = bid & 15;     // 0..15  N tile
    const int arow0 = tm * 256;
    const int brow0 = tn * 256;

    // staging: thread covers rows srow, srow+64 of a 128-row half, 16B chunk.
    const int srow  = tid >> 3;
    const int scole = (((tid & 7) * 16) ^ ((srow & 7) << 4)) >> 1;
    const int sldsb = tid * 16;

    // fragment reads (proven conflict-free r2/r3 pattern):
    // row = base + (lane&15); byte = kx0 / kx1 (kk halves).
    const int l15 = lane & 15;
    const int kx0 = ((lane >> 4) * 16) ^ ((lane & 7) << 4);
    const int kx1 = kx0 ^ 64;
    const int abase0 = (wm * 128 + l15) * 128;
    const int bbase0 = 32768 + (wn * 64 + l15) * 128;

    f32x4 acc[8][4] = {};
    bf16x8 af[8][2], bf[4][2];

#define STAGE_HALF(mat, grow0, t, ldsbase) do {                               \
        const unsigned short* _s =                                            \
            (mat) + ((grow0) + srow) * INF + (t) * 64 + scole;                \
        async_copy16(_s, lds + (ldsbase) + sldsb);                            \
        async_copy16(_s + 64 * INF, lds + (ldsbase) + 8192 + sldsb);          \
    } while (0)

#define LDA(DB, m, kh) (*(const bf16x8*)(lds + (DB) + abase0 + (m) * 2048 + ((kh) ? kx1 : kx0)))
#define LDB(DB, n, kh) (*(const bf16x8*)(lds + (DB) + bbase0 + (n) * 2048 + ((kh) ? kx1 : kx0)))
#define MFMA(a, b, c) __builtin_amdgcn_mfma_f32_16x16x32_bf16((a), (b), (c), 0, 0, 0)
#define BARRIER() do { asm volatile("" ::: "memory");                         \
                       __builtin_amdgcn_s_barrier();                          \
                       asm volatile("" ::: "memory"); } while (0)

#define TILE(CUR, OTH, s) do {                                                \
    /* ---- reads, progressive dependence order ---- */                       \
    _Pragma("unroll") for (int m = 0; m < 4; ++m) af[m][0] = LDA(CUR, m, 0);  \
    _Pragma("unroll") for (int n = 0; n < 4; ++n) bf[n][0] = LDB(CUR, n, 0);  \
    _Pragma("unroll") for (int m = 4; m < 8; ++m) af[m][0] = LDA(CUR, m, 0);  \
    _Pragma("unroll") for (int n = 0; n < 4; ++n) bf[n][1] = LDB(CUR, n, 1);  \
    _Pragma("unroll") for (int m = 0; m < 8; ++m) af[m][1] = LDA(CUR, m, 1);  \
    /* ---- stage tile s+1 -> OTH ---- */                                     \
    if ((s) + 1 < KT) {                                                       \
        STAGE_HALF(Xb, arow0,       (s) + 1, (OTH) + 0);                      \
        STAGE_HALF(Xb, arow0 + 128, (s) + 1, (OTH) + 16384);                  \
        STAGE_HALF(Wb, brow0,       (s) + 1, (OTH) + 32768);                  \
        STAGE_HALF(Wb, brow0 + 128, (s) + 1, (OTH) + 49152);                  \
    }                                                                         \
    /* ---- 64 MFMA; compiler interleaves lgkmcnt partial waits ---- */       \
    __builtin_amdgcn_s_setprio(1);                                            \
    _Pragma("unroll") for (int m = 0; m < 4; ++m)                             \
        _Pragma("unroll") for (int n = 0; n < 4; ++n)                         \
            acc[m][n] = MFMA(af[m][0], bf[n][0], acc[m][n]);                  \
    _Pragma("unroll") for (int m = 4; m < 8; ++m)                             \
        _Pragma("unroll") for (int n = 0; n < 4; ++n)                         \
            acc[m][n] = MFMA(af[m][0], bf[n][0], acc[m][n]);                  \
    _Pragma("unroll") for (int m = 0; m < 8; ++m)                             \
        _Pragma("unroll") for (int n = 0; n < 4; ++n)                         \
            acc[m][n] = MFMA(af[m][1], bf[n][1], acc[m][n]);                  \
    __builtin_amdgcn_s_setprio(0);                                            \
    asm volatile("s_waitcnt vmcnt(0)" ::: "memory");                          \
    BARRIER();                                                                \
} while (0)

    // ---- prologue: tile 0 -> buf0 ----
    STAGE_HALF(Xb, arow0,       0, 0);
    STAGE_HALF(Xb, arow0 + 128, 0, 16384);
    STAGE_HALF(Wb, brow0,       0, 32768);
    STAGE_HALF(Wb, brow0 + 128, 0, 49152);
    asm volatile("s_waitcnt vmcnt(0)" ::: "memory");
    BARRIER();

    for (int s = 0; s < KT; s += 2) {
        TILE(0, 65536, s);
        TILE(65536, 0, s + 1);
    }

    // ---- epilogue: C = acc + bias ----
#pragma unroll
    for (int n = 0; n < 4; ++n) {
        const int gcol = brow0 + wn * 64 + n * 16 + l15;
        const float bv = bias[gcol];
#pragma unroll
        for (int m = 0; m < 8; ++m) {
            const int grow = arow0 + wm * 128 + m * 16 + (lane >> 4) * 4;
#pragma unroll
            for (int rg = 0; rg < 4; ++rg)
                C[(grow + rg) * OUTF + gcol] = acc[m][n][rg] + bv;
        }
    }
#undef STAGE_HALF
#undef LDA
#undef LDB
#undef MFMA
#undef BARRIER
#undef TILE
}

// ---------------------------------------------------------------------------
extern "C" void kernel_launch(void* const* d_in, const int* in_sizes, int n_in,
                              void* d_out, int out_size, void* d_ws, size_t ws_size,
                              hipStream_t stream) {
    const float* x    = (const float*)d_in[0];   // [4,2048,4096]
    const float* bw   = (const float*)d_in[1];   // [4096,4096]
    const float* bb   = (const float*)d_in[2];   // [4096]
    const float* spec = (const float*)d_in[3];   // [10000]
    const float* ha   = (const float*)d_in[4];   // [16,4096]
    const int*   idx  = (const int*)d_in[5];     // [10000]
    float* out = (float*)d_out;

    char* ws = (char*)d_ws;
    float*          Bbuf = (float*)ws;                                // 256 KB
    unsigned short* Wb   = (unsigned short*)(ws + 262144);            // 32 MB
    unsigned short* Xb   = (unsigned short*)(ws + 262144 + 33554432); // 64 MB
    int2*           cjk  = (int2*)(ws + 262144 + 33554432 + 67108864);// 128 KB
    int*            ccnt = (int*)(ws + 262144 + 33554432 + 67108864 + 131072);

    compact_kernel<<<4, 256, 0, stream>>>(spec, idx, cjk, ccnt);
    buildB_kernel<<<1024, 256, 0, stream>>>(cjk, ccnt, Bbuf);
    build_w_kernel<<<512, 256, 0, stream>>>(bw, ha, Bbuf, Wb);
    cvt_x_kernel<<<2048, 256, 0, stream>>>((const float4*)x, (uint2*)Xb,
                                           (MDIM * INF) / 4);
    gemm256_kernel<<<512, 512, 0, stream>>>(Xb, Wb, bb, out);
}

// Round 7
// 405.439 us; speedup vs baseline: 1.3087x; 1.3087x over previous
//
#include <hip/hip_runtime.h>
#include <hip/hip_bf16.h>

// ---------------------------------------------------------------------------
// HoRA linear: out = x @ (base_w + (150*ifft2(sparse_spectrum)) @ A)^T + b
// M=8192, N=4096, K=4096.  bf16 MFMA GEMM with f32 accumulate.
// GEMM: 256x256 tile, BK=64, 8 waves, m201-style 8-phase/2-K-tile schedule,
// counted vmcnt(4) at P4/P8 only, XOR-swizzled LDS, setprio around MFMA.
// ---------------------------------------------------------------------------

#define OUTF 4096
#define INF  4096
#define NFREQ 10000
#define MDIM 8192
#define KT   (INF / 64)

typedef __attribute__((ext_vector_type(8))) short bf16x8;
typedef __attribute__((ext_vector_type(4))) float f32x4;

__device__ __forceinline__ unsigned int bf16pack2(float a, float b) {
    unsigned int ua = __builtin_bit_cast(unsigned int, a);
    unsigned int ub = __builtin_bit_cast(unsigned int, b);
    ua = (ua + 0x7fffu + ((ua >> 16) & 1u)) >> 16;          // RNE
    ub = (ub + 0x7fffu + ((ub >> 16) & 1u)) & 0xffff0000u;  // RNE, keep high
    return ua | ub;
}

__device__ __forceinline__ void async_copy16(const void* g, void* l) {
    __builtin_amdgcn_global_load_lds(
        (__attribute__((address_space(1))) void*)(g),
        (__attribute__((address_space(3))) void*)(l),
        16, 0, 0);
}

// ---------------------------------------------------------------------------
// Kernel 1a: compact nnz per chunk (4 blocks, deterministic ballot prefix).
// ---------------------------------------------------------------------------
__global__ __launch_bounds__(256) void compact_kernel(
        const float* __restrict__ spectrum, const int* __restrict__ idx,
        int2* __restrict__ cjk, int* __restrict__ ccnt) {
    const int p   = blockIdx.x;          // chunk 0..3
    const int tid = threadIdx.x;
    const int wv  = tid >> 6, ln = tid & 63;
    __shared__ int wcnt[4];
    int cnt = 0;
    for (int i0 = wv * 64; i0 < NFREQ; i0 += 256) {
        const int i = i0 + ln;
        bool m = (i < NFREQ) && ((idx[i] >> 14) == p);
        cnt += __popcll(__ballot(m));
    }
    if (ln == 0) wcnt[wv] = cnt;
    __syncthreads();
    int base = 0;
    for (int w = 0; w < wv; ++w) base += wcnt[w];
    for (int i0 = wv * 64; i0 < NFREQ; i0 += 256) {
        const int i = i0 + ln;
        bool m = false; int id = 0;
        if (i < NFREQ) { id = idx[i]; m = ((id >> 14) == p); }
        unsigned long long bal = __ballot(m);
        if (m) {
            int pos = base + __popcll(bal & ((1ull << ln) - 1ull));
            if (pos < 4096)
                cjk[p * 4096 + pos] =
                    make_int2(id & 16383, __builtin_bit_cast(int, spectrum[i]));
        }
        base += __popcll(bal);
    }
    if (tid == 0) {
        int t = wcnt[0] + wcnt[1] + wcnt[2] + wcnt[3];
        ccnt[p] = (t < 4096) ? t : 4096;
    }
}

// ---------------------------------------------------------------------------
// Kernel 1b: B[o][r] = (150/16384) * sum_nnz val * cos(2*pi*phase/16384)
// ---------------------------------------------------------------------------
__global__ __launch_bounds__(256) void buildB_kernel(
        const int2* __restrict__ cjk, const int* __restrict__ ccnt,
        float* __restrict__ Bout) {
    __shared__ int2  s_jkv[4096];
    __shared__ float s_part[4][64];
    const int tid  = threadIdx.x;
    const int gid0 = blockIdx.x * 64;
    const int p    = gid0 >> 14;
    const int cnt  = ccnt[p];
    for (int t = tid; t < cnt; t += 256) s_jkv[t] = cjk[p * 4096 + t];
    __syncthreads();
    const int qtr  = tid >> 6;
    const int ol   = tid & 63;
    const int gid  = gid0 + ol;
    const int o    = gid >> 4;
    const int r    = gid & 15;
    const int m    = o & 1023;
    const int qlen = (cnt + 3) >> 2;
    const int t0   = qtr * qlen;
    const int t1   = (t0 + qlen < cnt) ? t0 + qlen : cnt;
    const float c  = 6.283185307179586f / 16384.f;
    float acc = 0.f;
    for (int t = t0; t < t1; ++t) {
        const int2 jv = s_jkv[t];
        const int j = jv.x >> 4, k = jv.x & 15;
        int ph = (((j * m) & 1023) << 4) + (((k * r) & 15) << 10);
        acc += __builtin_bit_cast(float, jv.y) * __cosf((float)(ph & 16383) * c);
    }
    s_part[qtr][ol] = acc;
    __syncthreads();
    if (tid < 64) {
        float s = s_part[0][tid] + s_part[1][tid] + s_part[2][tid] + s_part[3][tid];
        Bout[gid0 + tid] = s * (150.f / 16384.f);
    }
}

// ---------------------------------------------------------------------------
// Kernel 2: W_bf16[n][k] = bf16(base_w[n][k] + sum_r Bs[n][r] * A[r][k])
// ---------------------------------------------------------------------------
__global__ __launch_bounds__(256) void build_w_kernel(
        const float* __restrict__ bw, const float* __restrict__ A,
        const float* __restrict__ Bs, unsigned short* __restrict__ W) {
    const int n0 = blockIdx.x * 8;
    __shared__ float sB[8][16];
    if (threadIdx.x < 128)
        ((float*)sB)[threadIdx.x] = Bs[n0 * 16 + threadIdx.x];
    __syncthreads();
    const float4* A4 = (const float4*)A;
    const float4* bw4 = (const float4*)bw;
    uint2* W2 = (uint2*)W;
#pragma unroll 1
    for (int q = 0; q < 4; ++q) {
        const int c4 = threadIdx.x + q * 256;
        float4 a[16];
#pragma unroll
        for (int r = 0; r < 16; ++r) a[r] = A4[r * 1024 + c4];
#pragma unroll 1
        for (int nn = 0; nn < 8; ++nn) {
            const int n = n0 + nn;
            float4 wv = bw4[n * 1024 + c4];
#pragma unroll
            for (int r = 0; r < 16; ++r) {
                float s = sB[nn][r];
                wv.x += s * a[r].x; wv.y += s * a[r].y;
                wv.z += s * a[r].z; wv.w += s * a[r].w;
            }
            W2[n * 1024 + c4] = make_uint2(bf16pack2(wv.x, wv.y),
                                           bf16pack2(wv.z, wv.w));
        }
    }
}

// ---------------------------------------------------------------------------
// Kernel 3: x (f32) -> bf16
// ---------------------------------------------------------------------------
__global__ __launch_bounds__(256) void cvt_x_kernel(
        const float4* __restrict__ x, uint2* __restrict__ xb, int n4) {
    for (int i = blockIdx.x * blockDim.x + threadIdx.x; i < n4;
         i += gridDim.x * blockDim.x) {
        float4 v = x[i];
        xb[i] = make_uint2(bf16pack2(v.x, v.y), bf16pack2(v.z, v.w));
    }
}

// ---------------------------------------------------------------------------
// Kernel 4: 256x256-tile 8-wave bf16 GEMM, 8-phase/2-K-tile schedule.
// Regions per buffer: A0=0 A1=16K B0=32K B1=48K. Per-wave reads: its A-half
// in P1&P3 (quadrant m-halves), its B-half in P1(bfa)&P2(bfb), plus hidden
// bfa reads after the P4/P8 barriers (next tile's B, just retired by vmcnt).
// Stage rotation (1 half/phase): P1:bA1(O) P2:bB1(O) P3:B0(E+2) P4:A0(E+2)
// P5:A1(E+2) P6:B1(E+2) P7:bB0(E+3) P8:bA0(E+3); every stage >=2 barriers
// after that region's last read. vmcnt(4) at P4 (retires buf1 tile O) and
// P8 (retires buf0 tile E+2); 2 halves always in flight in steady state.
// ---------------------------------------------------------------------------
__global__ __launch_bounds__(512, 2) void gemm256_kernel(
        const unsigned short* __restrict__ Xb,
        const unsigned short* __restrict__ Wb,
        const float* __restrict__ bias, float* __restrict__ C) {
    __shared__ __align__(1024) char lds[131072];

    const int tid  = threadIdx.x;
    const int lane = tid & 63;
    const int wid  = tid >> 6;
    const int wm   = wid >> 2;   // 0..1
    const int wn   = wid & 3;    // 0..3

    // XCD-bijective swizzle: nwg=512, divisible by 8.
    int bid = blockIdx.x;
    bid = (bid & 7) * 64 + (bid >> 3);
    const int tm = bid >> 4;     // 0..31  M tile
    const int tn = bid & 15;     // 0..15  N tile
    const int arow0 = tm * 256;
    const int brow0 = tn * 256;

    // staging: thread covers rows srow, srow+64 of a 128-row half, 16B chunk.
    const int srow  = tid >> 3;
    const int scole = (((tid & 7) * 16) ^ ((srow & 7) << 4)) >> 1;
    const int sldsb = tid * 16;

    // fragment reads (proven conflict-free pattern): row = base + (lane&15).
    const int l15 = lane & 15;
    const int kx0 = ((lane >> 4) * 16) ^ ((lane & 7) << 4);
    const int kx1 = kx0 ^ 64;
    const int abase0 = (wm * 128 + l15) * 128;
    const int bbase0 = 32768 + (wn * 64 + l15) * 128;

    f32x4 acc[8][4] = {};
    bf16x8 af[4][2], bfa[2][2], bfb[2][2];

#define STAGE_HALF(mat, grow0, t, ldsbase) do {                               \
        const unsigned short* _s =                                            \
            (mat) + ((grow0) + srow) * INF + (t) * 64 + scole;                \
        async_copy16(_s, lds + (ldsbase) + sldsb);                            \
        async_copy16(_s + 64 * INF, lds + (ldsbase) + 8192 + sldsb);          \
    } while (0)

#define LDA(DB, m, kh) (*(const bf16x8*)(lds + (DB) + abase0 + (m) * 2048 + ((kh) ? kx1 : kx0)))
#define LDB(DB, n, kh) (*(const bf16x8*)(lds + (DB) + bbase0 + (n) * 2048 + ((kh) ? kx1 : kx0)))
#define MFMA(a, b, c) __builtin_amdgcn_mfma_f32_16x16x32_bf16((a), (b), (c), 0, 0, 0)
#define BARRIER() do { asm volatile("" ::: "memory");                         \
                       __builtin_amdgcn_s_barrier();                          \
                       asm volatile("" ::: "memory"); } while (0)
#define LGKM0()  asm volatile("s_waitcnt lgkmcnt(0)" ::: "memory")

// Quadrant MFMA: rows mh*4.., cols nh*2.. ; uses af + (B ? bfb : bfa)
#define QMFMA(mh, BF)                                                         \
    __builtin_amdgcn_s_setprio(1);                                            \
    _Pragma("unroll") for (int ks = 0; ks < 2; ++ks)                          \
        _Pragma("unroll") for (int m = 0; m < 4; ++m)                         \
            _Pragma("unroll") for (int n = 0; n < 2; ++n)                     \
                acc[(mh) * 4 + m][(BF) * 2 + n] =                             \
                    MFMA(af[m][ks], ((BF) ? bfb : bfa)[n][ks],                \
                         acc[(mh) * 4 + m][(BF) * 2 + n]);                    \
    __builtin_amdgcn_s_setprio(0)

#define RD_AF(DB, mh)                                                         \
    _Pragma("unroll") for (int m = 0; m < 4; ++m) {                           \
        af[m][0] = LDA(DB, (mh) * 4 + m, 0);                                  \
        af[m][1] = LDA(DB, (mh) * 4 + m, 1); }
#define RD_BFA(DB)                                                            \
    _Pragma("unroll") for (int n = 0; n < 2; ++n) {                           \
        bfa[n][0] = LDB(DB, n, 0); bfa[n][1] = LDB(DB, n, 1); }
#define RD_BFB(DB)                                                            \
    _Pragma("unroll") for (int n = 0; n < 2; ++n) {                           \
        bfb[n][0] = LDB(DB, n + 2, 0); bfb[n][1] = LDB(DB, n + 2, 1); }

#define PAIR(CUR, OTH, s) do {                                                \
    /* P1: af<-CUR.A(m0-3); stage bA1(O)->OTH; Q(0,0)E */                     \
    RD_AF(CUR, 0);                                                            \
    STAGE_HALF(Xb, arow0 + 128, (s) + 1, (OTH) + 16384);                      \
    BARRIER(); LGKM0(); QMFMA(0, 0); BARRIER();                               \
    /* P2: bfb<-CUR.B(n2-3); stage bB1(O)->OTH; Q(0,1)E */                    \
    RD_BFB(CUR);                                                              \
    STAGE_HALF(Wb, brow0 + 128, (s) + 1, (OTH) + 49152);                      \
    BARRIER(); LGKM0(); QMFMA(0, 1); BARRIER();                               \
    /* P3: af<-CUR.A(m4-7); stage B0(E+2)->CUR; Q(1,0)E */                    \
    RD_AF(CUR, 1);                                                            \
    if ((s) + 2 < KT) STAGE_HALF(Wb, brow0, (s) + 2, (CUR) + 32768);          \
    BARRIER(); LGKM0(); QMFMA(1, 0); BARRIER();                               \
    /* P4: stage A0(E+2)->CUR; vmcnt; bfa<-OTH.B(n0-1); Q(1,1)E */            \
    if ((s) + 2 < KT) {                                                       \
        STAGE_HALF(Xb, arow0, (s) + 2, (CUR) + 0);                            \
        asm volatile("s_waitcnt vmcnt(4)" ::: "memory");                      \
    } else { asm volatile("s_waitcnt vmcnt(0)" ::: "memory"); }               \
    BARRIER();                                                                \
    RD_BFA(OTH);                                                              \
    QMFMA(1, 1); BARRIER();                                                   \
    /* P5: af<-OTH.A(m0-3); stage A1(E+2)->CUR; Q(0,0)O */                    \
    RD_AF(OTH, 0);                                                            \
    if ((s) + 2 < KT) STAGE_HALF(Xb, arow0 + 128, (s) + 2, (CUR) + 16384);    \
    BARRIER(); LGKM0(); QMFMA(0, 0); BARRIER();                               \
    /* P6: bfb<-OTH.B(n2-3); stage B1(E+2)->CUR; Q(0,1)O */                   \
    RD_BFB(OTH);                                                              \
    if ((s) + 2 < KT) STAGE_HALF(Wb, brow0 + 128, (s) + 2, (CUR) + 49152);    \
    BARRIER(); LGKM0(); QMFMA(0, 1); BARRIER();                               \
    /* P7: af<-OTH.A(m4-7); stage bB0(E+3)->OTH; Q(1,0)O */                   \
    RD_AF(OTH, 1);                                                            \
    if ((s) + 3 < KT) STAGE_HALF(Wb, brow0, (s) + 3, (OTH) + 32768);          \
    BARRIER(); LGKM0(); QMFMA(1, 0); BARRIER();                               \
    /* P8: stage bA0(E+3)->OTH; vmcnt; bfa<-CUR.B(n0-1) [tile E+2]; Q(1,1)O */\
    if ((s) + 3 < KT) {                                                       \
        STAGE_HALF(Xb, arow0, (s) + 3, (OTH) + 0);                            \
        asm volatile("s_waitcnt vmcnt(4)" ::: "memory");                      \
    } else { asm volatile("s_waitcnt vmcnt(0)" ::: "memory"); }               \
    BARRIER();                                                                \
    if ((s) + 2 < KT) { RD_BFA(CUR); }                                        \
    QMFMA(1, 1); BARRIER();                                                   \
} while (0)

    // ---- prologue: buf0 = tile0 (B0,A0,A1,B1), buf1 = bB0,bA0 of tile1 ----
    STAGE_HALF(Wb, brow0,       0, 32768);
    STAGE_HALF(Xb, arow0,       0, 0);
    STAGE_HALF(Xb, arow0 + 128, 0, 16384);
    STAGE_HALF(Wb, brow0 + 128, 0, 49152);
    STAGE_HALF(Wb, brow0,       1, 65536 + 32768);
    STAGE_HALF(Xb, arow0,       1, 65536 + 0);
    asm volatile("s_waitcnt vmcnt(4)" ::: "memory");
    BARRIER();
    RD_BFA(0);   // tile0's B(n0-1) from buf0

    for (int s = 0; s < KT; s += 2)
        PAIR(0, 65536, s);

    // ---- epilogue: C = acc + bias ----
#pragma unroll
    for (int n = 0; n < 4; ++n) {
        const int gcol = brow0 + wn * 64 + n * 16 + l15;
        const float bv = bias[gcol];
#pragma unroll
        for (int m = 0; m < 8; ++m) {
            const int grow = arow0 + wm * 128 + m * 16 + (lane >> 4) * 4;
#pragma unroll
            for (int rg = 0; rg < 4; ++rg)
                C[(grow + rg) * OUTF + gcol] = acc[m][n][rg] + bv;
        }
    }
#undef STAGE_HALF
#undef LDA
#undef LDB
#undef MFMA
#undef BARRIER
#undef LGKM0
#undef QMFMA
#undef RD_AF
#undef RD_BFA
#undef RD_BFB
#undef PAIR
}

// ---------------------------------------------------------------------------
extern "C" void kernel_launch(void* const* d_in, const int* in_sizes, int n_in,
                              void* d_out, int out_size, void* d_ws, size_t ws_size,
                              hipStream_t stream) {
    const float* x    = (const float*)d_in[0];   // [4,2048,4096]
    const float* bw   = (const float*)d_in[1];   // [4096,4096]
    const float* bb   = (const float*)d_in[2];   // [4096]
    const float* spec = (const float*)d_in[3];   // [10000]
    const float* ha   = (const float*)d_in[4];   // [16,4096]
    const int*   idx  = (const int*)d_in[5];     // [10000]
    float* out = (float*)d_out;

    char* ws = (char*)d_ws;
    float*          Bbuf = (float*)ws;                                // 256 KB
    unsigned short* Wb   = (unsigned short*)(ws + 262144);            // 32 MB
    unsigned short* Xb   = (unsigned short*)(ws + 262144 + 33554432); // 64 MB
    int2*           cjk  = (int2*)(ws + 262144 + 33554432 + 67108864);// 128 KB
    int*            ccnt = (int*)(ws + 262144 + 33554432 + 67108864 + 131072);

    compact_kernel<<<4, 256, 0, stream>>>(spec, idx, cjk, ccnt);
    buildB_kernel<<<1024, 256, 0, stream>>>(cjk, ccnt, Bbuf);
    build_w_kernel<<<512, 256, 0, stream>>>(bw, ha, Bbuf, Wb);
    cvt_x_kernel<<<2048, 256, 0, stream>>>((const float4*)x, (uint2*)Xb,
                                           (MDIM * INF) / 4);
    gemm256_kernel<<<512, 512, 0, stream>>>(Xb, Wb, bb, out);
}